// Round 6
// baseline (333.173 us; speedup 1.0000x reference)
//
#include <hip/hip_runtime.h>
#include <math.h>

#define HID 1024
#define NH  16
#define HD  64
#define NB  4
#define SL  2048
#define MROWS (NB * SL)   // 8192

typedef __attribute__((ext_vector_type(8))) short short8;
typedef __attribute__((ext_vector_type(4))) float f32x4;
typedef unsigned short ushort_t;
typedef unsigned int uint_t;

// fp32 -> bf16 bits, round-to-nearest-even
__device__ __forceinline__ uint_t f2bf(float x) {
    union { float f; uint_t u; } a; a.f = x;
    return (a.u + 0x7fffu + ((a.u >> 16) & 1u)) >> 16;
}

// async global->LDS, 16B per lane; LDS dest = wave-uniform base + lane*16
__device__ __forceinline__ void load_lds16(const void* g, void* l) {
    __builtin_amdgcn_global_load_lds(
        (const __attribute__((address_space(1))) void*)g,
        (__attribute__((address_space(3))) void*)l, 16, 0, 0);
}

// ---------------------------------------------------------------------------
// GEMM core: C(128x128) = A @ B^T, bf16, BK=64 (16 k-iters, 32 MFMA/wave/iter).
// LDS rows are 128 B = exactly 32 banks (row drops out of bank equation);
// chunks XOR-swizzled with r&7 (== c&7 at read) -> fragment b128 reads spread
// evenly over the 8 bank-groups.
// ---------------------------------------------------------------------------
__device__ __forceinline__ void gemm_core_bk64(
    const ushort_t* __restrict__ A, const ushort_t* __restrict__ B,
    const int m0, const int n0, ushort_t* As, ushort_t* Bs, f32x4 (&acc)[4][4])
{
    const int tid = threadIdx.x;
    const int w = tid >> 6, lane = tid & 63;
    const int wm = (w & 1) << 6, wn = (w >> 1) << 6;
    const int c = lane & 15, quad = lane >> 4;

    for (int k0 = 0; k0 < HID; k0 += 64) {
        __syncthreads();
        #pragma unroll
        for (int rd = 0; rd < 4; ++rd) {
            const int g = rd * 4 + w;            // wave-uniform group 0..15
            const int idx = g * 64 + lane;       // 16B-chunk id, 0..1023
            const int r = idx >> 3, sc = idx & 7;
            const int dc = sc ^ (r & 7);         // fetch permuted chunk
            load_lds16(&A[(size_t)(m0 + r) * HID + k0 + dc * 8], As + g * 512);
            load_lds16(&B[(size_t)(n0 + r) * HID + k0 + dc * 8], Bs + g * 512);
        }
        __syncthreads();

        #pragma unroll
        for (int ks = 0; ks < 2; ++ks) {
            short8 af[4], bf[4];
            #pragma unroll
            for (int i = 0; i < 4; ++i) {
                const int ra = wm + i * 16 + c;
                const int rb = wn + i * 16 + c;
                af[i] = *(const short8*)
                    &As[ra * 64 + ((((ks << 2) + quad) ^ (c & 7)) << 3)];
                bf[i] = *(const short8*)
                    &Bs[rb * 64 + ((((ks << 2) + quad) ^ (c & 7)) << 3)];
            }
            #pragma unroll
            for (int i = 0; i < 4; ++i)
                #pragma unroll
                for (int j = 0; j < 4; ++j)
                    acc[i][j] = __builtin_amdgcn_mfma_f32_16x16x32_bf16(
                        af[i], bf[j], acc[i][j], 0, 0, 0);
        }
    }
}

// ---------------------------------------------------------------------------
// fp32 -> bf16 conversion: 12 segments of 1M elems (x = 8 segs, 4 weights)
// ---------------------------------------------------------------------------
__global__ __launch_bounds__(256) void cvt_bf16_kernel(
    const float* __restrict__ x,
    const float* __restrict__ wq, const float* __restrict__ wk,
    const float* __restrict__ wv, const float* __restrict__ wo,
    ushort_t* __restrict__ xb, ushort_t* __restrict__ wqb,
    ushort_t* __restrict__ wkb, ushort_t* __restrict__ wvb,
    ushort_t* __restrict__ wob)
{
    const int seg = blockIdx.y;
    const float* src; ushort_t* dst;
    if (seg < 8)       { src = x + (size_t)seg * 1048576; dst = xb + (size_t)seg * 1048576; }
    else if (seg == 8) { src = wq; dst = wqb; }
    else if (seg == 9) { src = wk; dst = wkb; }
    else if (seg == 10){ src = wv; dst = wvb; }
    else               { src = wo; dst = wob; }
    const int i = (blockIdx.x * 256 + threadIdx.x) * 8;
    const float4 a = *(const float4*)&src[i];
    const float4 b = *(const float4*)&src[i + 4];
    uint4 o;
    o.x = f2bf(a.x) | (f2bf(a.y) << 16);
    o.y = f2bf(a.z) | (f2bf(a.w) << 16);
    o.z = f2bf(b.x) | (f2bf(b.y) << 16);
    o.w = f2bf(b.z) | (f2bf(b.w) << 16);
    *(uint4*)&dst[i] = o;
}

// ---------------------------------------------------------------------------
// QKV projection. grid (8 n-tiles, 64 m-tiles, 3 weights); 128x128 tile.
// Q pre-scaled by 0.125*log2(e); K as (B,H,S,D); V^T as (B,H,D,S).
// ---------------------------------------------------------------------------
__global__ __launch_bounds__(256) void qkv_mfma_kernel(
    const ushort_t* __restrict__ xb,
    const ushort_t* __restrict__ wqb, const ushort_t* __restrict__ wkb,
    const ushort_t* __restrict__ wvb,
    const float* __restrict__ bq, const float* __restrict__ bk,
    const float* __restrict__ bv,
    ushort_t* __restrict__ qo, ushort_t* __restrict__ ko,
    ushort_t* __restrict__ vo)
{
    __shared__ __align__(16) ushort_t As[128 * 64];   // 16 KB
    __shared__ __align__(16) ushort_t Bs[128 * 64];   // 16 KB

    const int wsel = blockIdx.z;
    const ushort_t* W    = (wsel == 0) ? wqb : (wsel == 1) ? wkb : wvb;
    const float*    bias = (wsel == 0) ? bq  : (wsel == 1) ? bk  : bv;
    const int m0 = blockIdx.y * 128, n0 = blockIdx.x * 128;

    f32x4 acc[4][4];
    const f32x4 zero = {0.f, 0.f, 0.f, 0.f};
    #pragma unroll
    for (int i = 0; i < 4; ++i)
        #pragma unroll
        for (int j = 0; j < 4; ++j) acc[i][j] = zero;

    gemm_core_bk64(xb, W, m0, n0, As, Bs, acc);

    const int tid = threadIdx.x;
    const int w = tid >> 6, lane = tid & 63;
    const int wm = (w & 1) << 6, wn = (w >> 1) << 6;
    const int c = lane & 15, quad = lane >> 4;
    // 0.125 (1/sqrt(64)) * log2(e): scores land in log2 domain
    const float qscale = (wsel == 0) ? 0.18033688f : 1.0f;

    #pragma unroll
    for (int j = 0; j < 4; ++j) {
        const int n_g = n0 + wn + j * 16 + c;
        const float bj = bias[n_g];
        const int h = n_g >> 6, d = n_g & 63;
        #pragma unroll
        for (int i = 0; i < 4; ++i) {
            const int mbase = m0 + wm + i * 16 + quad * 4;
            const int b = mbase >> 11;
            const int sbase = mbase & (SL - 1);
            if (wsel == 2) {
                ushort4 pk;
                pk.x = (ushort_t)f2bf(acc[i][j][0] + bj);
                pk.y = (ushort_t)f2bf(acc[i][j][1] + bj);
                pk.z = (ushort_t)f2bf(acc[i][j][2] + bj);
                pk.w = (ushort_t)f2bf(acc[i][j][3] + bj);
                *(ushort4*)&vo[(((size_t)(b * NH + h) * HD) + d) * SL + sbase] = pk;
            } else {
                ushort_t* dst = (wsel == 0) ? qo : ko;
                #pragma unroll
                for (int reg = 0; reg < 4; ++reg) {
                    const float v = (acc[i][j][reg] + bj) * qscale;
                    dst[(((size_t)(b * NH + h) * SL) + sbase + reg) * HD + d] =
                        (ushort_t)f2bf(v);
                }
            }
        }
    }
}

// ---------------------------------------------------------------------------
// MFMA flash attention, fixed-base softmax, 128-row q-tiles, 32 rows/wave:
// each kf/vf fragment read feeds 2 MFMAs (mi=0,1) -> LDS traffic per unit
// work -44% vs the 16-row/wave version (which was LDS-BW-bound at 128 us).
// grid (16 q-tiles, 64 b*h) = 1024 blocks; 34 KB LDS -> 4 blocks/CU (all
// resident). Key permutation: lane c's tile-ni key = 4c+ni.
// ---------------------------------------------------------------------------
__global__ __launch_bounds__(256) void attn_mfma_kernel(
    const ushort_t* __restrict__ q, const ushort_t* __restrict__ k,
    const ushort_t* __restrict__ vt, const int* __restrict__ mask,
    ushort_t* __restrict__ ao)
{
    __shared__ __align__(16) ushort_t Ks[64 * 64];    // 8 KB
    __shared__ __align__(16) ushort_t Vs[64 * 64];    // 8 KB
    __shared__ __align__(16) ushort_t Ps[128 * 72];   // 18 KB

    const int qt = blockIdx.x;    // 0..15
    const int bh = blockIdx.y;
    const int b = bh >> 4, h = bh & 15;
    const int tid = threadIdx.x;
    const int w = tid >> 6, lane = tid & 63;
    const int c = lane & 15, quad = lane >> 4;

    const ushort_t* qp = q  + (size_t)bh * SL * HD + (size_t)qt * 128 * HD;
    const ushort_t* kp = k  + (size_t)bh * SL * HD;
    const ushort_t* vp = vt + (size_t)bh * HD * SL;

    short8 qf[2][2];
    #pragma unroll
    for (int mi = 0; mi < 2; ++mi)
        #pragma unroll
        for (int ks = 0; ks < 2; ++ks)
            qf[mi][ks] = *(const short8*)&qp[(size_t)(w * 32 + mi * 16 + c) * HD
                                             + ks * 32 + quad * 8];

    float l_s[2][4] = {};
    f32x4 oa[2][4];
    const f32x4 zero = {0.f, 0.f, 0.f, 0.f};
    #pragma unroll
    for (int mi = 0; mi < 2; ++mi)
        #pragma unroll
        for (int ni = 0; ni < 4; ++ni) oa[mi][ni] = zero;

    for (int kt = 0; kt < SL / 64; ++kt) {
        __syncthreads();
        // K swizzle keyed (r>>2)&7 (QK^T reads row 4c+ni); V keyed r&7 (PV row ni*16+c)
        #pragma unroll
        for (int rd = 0; rd < 2; ++rd) {
            const int g = rd * 4 + w;
            const int t = g * 64 + lane;
            const int r = t >> 3, sc = t & 7;
            const int dck = sc ^ ((r >> 2) & 7);
            const int dcv = sc ^ (r & 7);
            load_lds16(&kp[(size_t)(kt * 64 + r) * HD + dck * 8], Ks + g * 512);
            load_lds16(&vp[(size_t)r * SL + kt * 64 + dcv * 8], Vs + g * 512);
        }
        __syncthreads();

        // S = Q @ K^T, log2 domain. Column c of tile ni = key 4c+ni.
        f32x4 sf[2][4];
        #pragma unroll
        for (int mi = 0; mi < 2; ++mi)
            #pragma unroll
            for (int ni = 0; ni < 4; ++ni) sf[mi][ni] = zero;
        #pragma unroll
        for (int ni = 0; ni < 4; ++ni) {
            const int krow = 4 * c + ni;
            #pragma unroll
            for (int ks = 0; ks < 2; ++ks) {
                const short8 kf = *(const short8*)
                    &Ks[krow * 64 + (((ks * 4 + quad) ^ (c & 7)) << 3)];
                #pragma unroll
                for (int mi = 0; mi < 2; ++mi)
                    sf[mi][ni] = __builtin_amdgcn_mfma_f32_16x16x32_bf16(
                        qf[mi][ks], kf, sf[mi][ni], 0, 0, 0);
            }
        }

        const int4 mzv = *(const int4*)&mask[b * SL + kt * 64 + 4 * c];
        const int mz[4] = {mzv.x, mzv.y, mzv.z, mzv.w};

        #pragma unroll
        for (int mi = 0; mi < 2; ++mi) {
            #pragma unroll
            for (int reg = 0; reg < 4; ++reg) {
                float p[4];
                #pragma unroll
                for (int ni = 0; ni < 4; ++ni) {
                    float pv = __builtin_amdgcn_exp2f(sf[mi][ni][reg]);
                    p[ni] = (mz[ni] == 0) ? 0.f : pv;
                }
                l_s[mi][reg] += (p[0] + p[1]) + (p[2] + p[3]);
                union { float f; uint_t u; } u0, u1, u2, u3;
                u0.f = p[0]; u1.f = p[1]; u2.f = p[2]; u3.f = p[3];
                uint2 pk;
                pk.x = __builtin_amdgcn_perm(u1.u, u0.u, 0x07060302u);
                pk.y = __builtin_amdgcn_perm(u3.u, u2.u, 0x07060302u);
                *(uint2*)&Ps[(w * 32 + mi * 16 + quad * 4 + reg) * 72 + 4 * c] = pk;
            }
        }
        // wave-local LDS round-trip: no barrier needed

        short8 pf[2][2];
        #pragma unroll
        for (int mi = 0; mi < 2; ++mi)
            #pragma unroll
            for (int ks = 0; ks < 2; ++ks)
                pf[mi][ks] = *(const short8*)
                    &Ps[(w * 32 + mi * 16 + c) * 72 + ks * 32 + quad * 8];
        #pragma unroll
        for (int ni = 0; ni < 4; ++ni) {
            const int n = ni * 16 + c;
            #pragma unroll
            for (int ks = 0; ks < 2; ++ks) {
                const short8 vf = *(const short8*)
                    &Vs[n * 64 + (((ks * 4 + quad) ^ (c & 7)) << 3)];
                #pragma unroll
                for (int mi = 0; mi < 2; ++mi)
                    oa[mi][ni] = __builtin_amdgcn_mfma_f32_16x16x32_bf16(
                        pf[mi][ks], vf, oa[mi][ni], 0, 0, 0);
            }
        }
    }

    #pragma unroll
    for (int mi = 0; mi < 2; ++mi) {
        #pragma unroll
        for (int reg = 0; reg < 4; ++reg) {
            float l = l_s[mi][reg];
            #pragma unroll
            for (int off = 1; off < 16; off <<= 1)
                l += __shfl_xor(l, off, 64);
            const float inv = 1.f / l;
            const int s_g = qt * 128 + w * 32 + mi * 16 + quad * 4 + reg;
            #pragma unroll
            for (int ni = 0; ni < 4; ++ni) {
                const int d = ni * 16 + c;
                ao[((size_t)(b * SL + s_g)) * HID + h * HD + d] =
                    (ushort_t)f2bf(oa[mi][ni][reg] * inv);
            }
        }
    }
}

// ---------------------------------------------------------------------------
// Output projection: out(fp32) = ao_bf @ Wo^T + bo. grid (8, 64).
// ---------------------------------------------------------------------------
__global__ __launch_bounds__(256) void out_mfma_kernel(
    const ushort_t* __restrict__ aob, const ushort_t* __restrict__ wob,
    const float* __restrict__ bo, float* __restrict__ out)
{
    __shared__ __align__(16) ushort_t As[128 * 64];
    __shared__ __align__(16) ushort_t Bs[128 * 64];

    const int m0 = blockIdx.y * 128, n0 = blockIdx.x * 128;

    f32x4 acc[4][4];
    const f32x4 zero = {0.f, 0.f, 0.f, 0.f};
    #pragma unroll
    for (int i = 0; i < 4; ++i)
        #pragma unroll
        for (int j = 0; j < 4; ++j) acc[i][j] = zero;

    gemm_core_bk64(aob, wob, m0, n0, As, Bs, acc);

    const int tid = threadIdx.x;
    const int w = tid >> 6, lane = tid & 63;
    const int wm = (w & 1) << 6, wn = (w >> 1) << 6;
    const int c = lane & 15, quad = lane >> 4;

    #pragma unroll
    for (int j = 0; j < 4; ++j) {
        const int n_g = n0 + wn + j * 16 + c;
        const float bj = bo[n_g];
        #pragma unroll
        for (int i = 0; i < 4; ++i) {
            const int mbase = m0 + wm + i * 16 + quad * 4;
            #pragma unroll
            for (int reg = 0; reg < 4; ++reg)
                out[(size_t)(mbase + reg) * HID + n_g] = acc[i][j][reg] + bj;
        }
    }
}

extern "C" void kernel_launch(void* const* d_in, const int* in_sizes, int n_in,
                              void* d_out, int out_size, void* d_ws, size_t ws_size,
                              hipStream_t stream)
{
    const float* x    = (const float*)d_in[0];
    const int*   mask = (const int*)d_in[1];
    const float* Wq   = (const float*)d_in[2];
    const float* bq   = (const float*)d_in[3];
    const float* Wk   = (const float*)d_in[4];
    const float* bk   = (const float*)d_in[5];
    const float* Wv   = (const float*)d_in[6];
    const float* bv   = (const float*)d_in[7];
    const float* Wo   = (const float*)d_in[8];
    const float* bo   = (const float*)d_in[9];
    float* out = (float*)d_out;

    ushort_t* p = (ushort_t*)d_ws;
    ushort_t* xb  = p; p += (size_t)MROWS * HID;
    ushort_t* wqb = p; p += (size_t)HID * HID;
    ushort_t* wkb = p; p += (size_t)HID * HID;
    ushort_t* wvb = p; p += (size_t)HID * HID;
    ushort_t* wob = p; p += (size_t)HID * HID;
    ushort_t* qb  = p; p += (size_t)MROWS * HID;
    ushort_t* kb  = p; p += (size_t)MROWS * HID;
    ushort_t* vtb = p; p += (size_t)MROWS * HID;
    ushort_t* aob = p; p += (size_t)MROWS * HID;

    cvt_bf16_kernel<<<dim3(512, 12), 256, 0, stream>>>(
        x, Wq, Wk, Wv, Wo, xb, wqb, wkb, wvb, wob);
    qkv_mfma_kernel<<<dim3(8, 64, 3), 256, 0, stream>>>(
        xb, wqb, wkb, wvb, bq, bk, bv, qb, kb, vtb);
    attn_mfma_kernel<<<dim3(16, 64), 256, 0, stream>>>(
        qb, kb, vtb, mask, aob);
    out_mfma_kernel<<<dim3(8, 64), 256, 0, stream>>>(
        aob, wob, bo, out);
}

// Round 7
// 291.544 us; speedup vs baseline: 1.1428x; 1.1428x over previous
//
#include <hip/hip_runtime.h>
#include <math.h>

#define HID 1024
#define NH  16
#define HD  64
#define NB  4
#define SL  2048
#define MROWS (NB * SL)   // 8192

typedef __attribute__((ext_vector_type(8))) short short8;
typedef __attribute__((ext_vector_type(4))) float f32x4;
typedef unsigned short ushort_t;
typedef unsigned int uint_t;

// fp32 -> bf16 bits, round-to-nearest-even
__device__ __forceinline__ uint_t f2bf(float x) {
    union { float f; uint_t u; } a; a.f = x;
    return (a.u + 0x7fffu + ((a.u >> 16) & 1u)) >> 16;
}

// async global->LDS, 16B per lane; LDS dest = wave-uniform base + lane*16
__device__ __forceinline__ void load_lds16(const void* g, void* l) {
    __builtin_amdgcn_global_load_lds(
        (const __attribute__((address_space(1))) void*)g,
        (__attribute__((address_space(3))) void*)l, 16, 0, 0);
}

// ---------------------------------------------------------------------------
// GEMM core: C(128x128) = A @ B^T, bf16, BK=64 (16 k-iters, 32 MFMA/wave/iter).
// LDS rows are 128 B = exactly 32 banks (row drops out of bank equation);
// chunks XOR-swizzled with r&7 (== c&7 at read) -> fragment b128 reads spread
// evenly over the 8 bank-groups.
// ---------------------------------------------------------------------------
__device__ __forceinline__ void gemm_core_bk64(
    const ushort_t* __restrict__ A, const ushort_t* __restrict__ B,
    const int m0, const int n0, ushort_t* As, ushort_t* Bs, f32x4 (&acc)[4][4])
{
    const int tid = threadIdx.x;
    const int w = tid >> 6, lane = tid & 63;
    const int wm = (w & 1) << 6, wn = (w >> 1) << 6;
    const int c = lane & 15, quad = lane >> 4;

    for (int k0 = 0; k0 < HID; k0 += 64) {
        __syncthreads();
        #pragma unroll
        for (int rd = 0; rd < 4; ++rd) {
            const int g = rd * 4 + w;            // wave-uniform group 0..15
            const int idx = g * 64 + lane;       // 16B-chunk id, 0..1023
            const int r = idx >> 3, sc = idx & 7;
            const int dc = sc ^ (r & 7);         // fetch permuted chunk
            load_lds16(&A[(size_t)(m0 + r) * HID + k0 + dc * 8], As + g * 512);
            load_lds16(&B[(size_t)(n0 + r) * HID + k0 + dc * 8], Bs + g * 512);
        }
        __syncthreads();

        #pragma unroll
        for (int ks = 0; ks < 2; ++ks) {
            short8 af[4], bf[4];
            #pragma unroll
            for (int i = 0; i < 4; ++i) {
                const int ra = wm + i * 16 + c;
                const int rb = wn + i * 16 + c;
                af[i] = *(const short8*)
                    &As[ra * 64 + ((((ks << 2) + quad) ^ (c & 7)) << 3)];
                bf[i] = *(const short8*)
                    &Bs[rb * 64 + ((((ks << 2) + quad) ^ (c & 7)) << 3)];
            }
            #pragma unroll
            for (int i = 0; i < 4; ++i)
                #pragma unroll
                for (int j = 0; j < 4; ++j)
                    acc[i][j] = __builtin_amdgcn_mfma_f32_16x16x32_bf16(
                        af[i], bf[j], acc[i][j], 0, 0, 0);
        }
    }
}

// ---------------------------------------------------------------------------
// fp32 -> bf16 conversion: 12 segments of 1M elems (x = 8 segs, 4 weights)
// ---------------------------------------------------------------------------
__global__ __launch_bounds__(256) void cvt_bf16_kernel(
    const float* __restrict__ x,
    const float* __restrict__ wq, const float* __restrict__ wk,
    const float* __restrict__ wv, const float* __restrict__ wo,
    ushort_t* __restrict__ xb, ushort_t* __restrict__ wqb,
    ushort_t* __restrict__ wkb, ushort_t* __restrict__ wvb,
    ushort_t* __restrict__ wob)
{
    const int seg = blockIdx.y;
    const float* src; ushort_t* dst;
    if (seg < 8)       { src = x + (size_t)seg * 1048576; dst = xb + (size_t)seg * 1048576; }
    else if (seg == 8) { src = wq; dst = wqb; }
    else if (seg == 9) { src = wk; dst = wkb; }
    else if (seg == 10){ src = wv; dst = wvb; }
    else               { src = wo; dst = wob; }
    const int i = (blockIdx.x * 256 + threadIdx.x) * 8;
    const float4 a = *(const float4*)&src[i];
    const float4 b = *(const float4*)&src[i + 4];
    uint4 o;
    o.x = f2bf(a.x) | (f2bf(a.y) << 16);
    o.y = f2bf(a.z) | (f2bf(a.w) << 16);
    o.z = f2bf(b.x) | (f2bf(b.y) << 16);
    o.w = f2bf(b.z) | (f2bf(b.w) << 16);
    *(uint4*)&dst[i] = o;
}

// ---------------------------------------------------------------------------
// QKV projection. grid (8 n-tiles, 64 m-tiles, 3 weights); 128x128 tile.
// Q pre-scaled by 0.125*log2(e); K as (B,H,S,D); V^T as (B,H,D,S).
// ---------------------------------------------------------------------------
__global__ __launch_bounds__(256) void qkv_mfma_kernel(
    const ushort_t* __restrict__ xb,
    const ushort_t* __restrict__ wqb, const ushort_t* __restrict__ wkb,
    const ushort_t* __restrict__ wvb,
    const float* __restrict__ bq, const float* __restrict__ bk,
    const float* __restrict__ bv,
    ushort_t* __restrict__ qo, ushort_t* __restrict__ ko,
    ushort_t* __restrict__ vo)
{
    __shared__ __align__(16) ushort_t As[128 * 64];   // 16 KB
    __shared__ __align__(16) ushort_t Bs[128 * 64];   // 16 KB

    const int wsel = blockIdx.z;
    const ushort_t* W    = (wsel == 0) ? wqb : (wsel == 1) ? wkb : wvb;
    const float*    bias = (wsel == 0) ? bq  : (wsel == 1) ? bk  : bv;
    const int m0 = blockIdx.y * 128, n0 = blockIdx.x * 128;

    f32x4 acc[4][4];
    const f32x4 zero = {0.f, 0.f, 0.f, 0.f};
    #pragma unroll
    for (int i = 0; i < 4; ++i)
        #pragma unroll
        for (int j = 0; j < 4; ++j) acc[i][j] = zero;

    gemm_core_bk64(xb, W, m0, n0, As, Bs, acc);

    const int tid = threadIdx.x;
    const int w = tid >> 6, lane = tid & 63;
    const int wm = (w & 1) << 6, wn = (w >> 1) << 6;
    const int c = lane & 15, quad = lane >> 4;
    // 0.125 (1/sqrt(64)) * log2(e): scores land in log2 domain
    const float qscale = (wsel == 0) ? 0.18033688f : 1.0f;

    #pragma unroll
    for (int j = 0; j < 4; ++j) {
        const int n_g = n0 + wn + j * 16 + c;
        const float bj = bias[n_g];
        const int h = n_g >> 6, d = n_g & 63;
        #pragma unroll
        for (int i = 0; i < 4; ++i) {
            const int mbase = m0 + wm + i * 16 + quad * 4;
            const int b = mbase >> 11;
            const int sbase = mbase & (SL - 1);
            if (wsel == 2) {
                ushort4 pk;
                pk.x = (ushort_t)f2bf(acc[i][j][0] + bj);
                pk.y = (ushort_t)f2bf(acc[i][j][1] + bj);
                pk.z = (ushort_t)f2bf(acc[i][j][2] + bj);
                pk.w = (ushort_t)f2bf(acc[i][j][3] + bj);
                *(ushort4*)&vo[(((size_t)(b * NH + h) * HD) + d) * SL + sbase] = pk;
            } else {
                ushort_t* dst = (wsel == 0) ? qo : ko;
                #pragma unroll
                for (int reg = 0; reg < 4; ++reg) {
                    const float v = (acc[i][j][reg] + bj) * qscale;
                    dst[(((size_t)(b * NH + h) * SL) + sbase + reg) * HD + d] =
                        (ushort_t)f2bf(v);
                }
            }
        }
    }
}

// ---------------------------------------------------------------------------
// MFMA flash attention, fixed-base softmax, 128-row q-tiles, 32 rows/wave.
// __launch_bounds__(256, 4): force <=128 unified regs (R6 allocated 132 ->
// occupancy halved to 2 blocks/CU; 4 more regs shaved doubles it back).
// LDS 34 KB x 4 blocks = 139 KB < 160 KB, so regs were the only blocker.
// ---------------------------------------------------------------------------
__global__ __launch_bounds__(256, 4) void attn_mfma_kernel(
    const ushort_t* __restrict__ q, const ushort_t* __restrict__ k,
    const ushort_t* __restrict__ vt, const int* __restrict__ mask,
    ushort_t* __restrict__ ao)
{
    __shared__ __align__(16) ushort_t Ks[64 * 64];    // 8 KB
    __shared__ __align__(16) ushort_t Vs[64 * 64];    // 8 KB
    __shared__ __align__(16) ushort_t Ps[128 * 72];   // 18 KB

    const int qt = blockIdx.x;    // 0..15
    const int bh = blockIdx.y;
    const int b = bh >> 4, h = bh & 15;
    const int tid = threadIdx.x;
    const int w = tid >> 6, lane = tid & 63;
    const int c = lane & 15, quad = lane >> 4;

    const ushort_t* qp = q  + (size_t)bh * SL * HD + (size_t)qt * 128 * HD;
    const ushort_t* kp = k  + (size_t)bh * SL * HD;
    const ushort_t* vp = vt + (size_t)bh * HD * SL;

    short8 qf[2][2];
    #pragma unroll
    for (int mi = 0; mi < 2; ++mi)
        #pragma unroll
        for (int ks = 0; ks < 2; ++ks)
            qf[mi][ks] = *(const short8*)&qp[(size_t)(w * 32 + mi * 16 + c) * HD
                                             + ks * 32 + quad * 8];

    float l_s[2][4] = {};
    f32x4 oa[2][4];
    const f32x4 zero = {0.f, 0.f, 0.f, 0.f};
    #pragma unroll
    for (int mi = 0; mi < 2; ++mi)
        #pragma unroll
        for (int ni = 0; ni < 4; ++ni) oa[mi][ni] = zero;

    for (int kt = 0; kt < SL / 64; ++kt) {
        __syncthreads();
        // K swizzle keyed (r>>2)&7 (QK^T reads row 4c+ni); V keyed r&7 (PV row ni*16+c)
        #pragma unroll
        for (int rd = 0; rd < 2; ++rd) {
            const int g = rd * 4 + w;
            const int t = g * 64 + lane;
            const int r = t >> 3, sc = t & 7;
            const int dck = sc ^ ((r >> 2) & 7);
            const int dcv = sc ^ (r & 7);
            load_lds16(&kp[(size_t)(kt * 64 + r) * HD + dck * 8], Ks + g * 512);
            load_lds16(&vp[(size_t)r * SL + kt * 64 + dcv * 8], Vs + g * 512);
        }
        __syncthreads();

        // S = Q @ K^T, log2 domain. Column c of tile ni = key 4c+ni.
        f32x4 sf[2][4];
        #pragma unroll
        for (int mi = 0; mi < 2; ++mi)
            #pragma unroll
            for (int ni = 0; ni < 4; ++ni) sf[mi][ni] = zero;
        #pragma unroll
        for (int ni = 0; ni < 4; ++ni) {
            const int krow = 4 * c + ni;
            #pragma unroll
            for (int ks = 0; ks < 2; ++ks) {
                const short8 kf = *(const short8*)
                    &Ks[krow * 64 + (((ks * 4 + quad) ^ (c & 7)) << 3)];
                #pragma unroll
                for (int mi = 0; mi < 2; ++mi)
                    sf[mi][ni] = __builtin_amdgcn_mfma_f32_16x16x32_bf16(
                        qf[mi][ks], kf, sf[mi][ni], 0, 0, 0);
            }
        }

        const int4 mzv = *(const int4*)&mask[b * SL + kt * 64 + 4 * c];
        const int mz[4] = {mzv.x, mzv.y, mzv.z, mzv.w};

        #pragma unroll
        for (int mi = 0; mi < 2; ++mi) {
            #pragma unroll
            for (int reg = 0; reg < 4; ++reg) {
                float p[4];
                #pragma unroll
                for (int ni = 0; ni < 4; ++ni) {
                    float pv = __builtin_amdgcn_exp2f(sf[mi][ni][reg]);
                    p[ni] = (mz[ni] == 0) ? 0.f : pv;
                }
                l_s[mi][reg] += (p[0] + p[1]) + (p[2] + p[3]);
                union { float f; uint_t u; } u0, u1, u2, u3;
                u0.f = p[0]; u1.f = p[1]; u2.f = p[2]; u3.f = p[3];
                uint2 pk;
                pk.x = __builtin_amdgcn_perm(u1.u, u0.u, 0x07060302u);
                pk.y = __builtin_amdgcn_perm(u3.u, u2.u, 0x07060302u);
                *(uint2*)&Ps[(w * 32 + mi * 16 + quad * 4 + reg) * 72 + 4 * c] = pk;
            }
        }
        // wave-local LDS round-trip: no barrier needed

        short8 pf[2][2];
        #pragma unroll
        for (int mi = 0; mi < 2; ++mi)
            #pragma unroll
            for (int ks = 0; ks < 2; ++ks)
                pf[mi][ks] = *(const short8*)
                    &Ps[(w * 32 + mi * 16 + c) * 72 + ks * 32 + quad * 8];
        #pragma unroll
        for (int ni = 0; ni < 4; ++ni) {
            const int n = ni * 16 + c;
            #pragma unroll
            for (int ks = 0; ks < 2; ++ks) {
                const short8 vf = *(const short8*)
                    &Vs[n * 64 + (((ks * 4 + quad) ^ (c & 7)) << 3)];
                #pragma unroll
                for (int mi = 0; mi < 2; ++mi)
                    oa[mi][ni] = __builtin_amdgcn_mfma_f32_16x16x32_bf16(
                        pf[mi][ks], vf, oa[mi][ni], 0, 0, 0);
            }
        }
    }

    #pragma unroll
    for (int mi = 0; mi < 2; ++mi) {
        #pragma unroll
        for (int reg = 0; reg < 4; ++reg) {
            float l = l_s[mi][reg];
            #pragma unroll
            for (int off = 1; off < 16; off <<= 1)
                l += __shfl_xor(l, off, 64);
            const float inv = 1.f / l;
            const int s_g = qt * 128 + w * 32 + mi * 16 + quad * 4 + reg;
            #pragma unroll
            for (int ni = 0; ni < 4; ++ni) {
                const int d = ni * 16 + c;
                ao[((size_t)(b * SL + s_g)) * HID + h * HD + d] =
                    (ushort_t)f2bf(oa[mi][ni][reg] * inv);
            }
        }
    }
}

// ---------------------------------------------------------------------------
// Output projection: out(fp32) = ao_bf @ Wo^T + bo. grid (8, 64).
// ---------------------------------------------------------------------------
__global__ __launch_bounds__(256) void out_mfma_kernel(
    const ushort_t* __restrict__ aob, const ushort_t* __restrict__ wob,
    const float* __restrict__ bo, float* __restrict__ out)
{
    __shared__ __align__(16) ushort_t As[128 * 64];
    __shared__ __align__(16) ushort_t Bs[128 * 64];

    const int m0 = blockIdx.y * 128, n0 = blockIdx.x * 128;

    f32x4 acc[4][4];
    const f32x4 zero = {0.f, 0.f, 0.f, 0.f};
    #pragma unroll
    for (int i = 0; i < 4; ++i)
        #pragma unroll
        for (int j = 0; j < 4; ++j) acc[i][j] = zero;

    gemm_core_bk64(aob, wob, m0, n0, As, Bs, acc);

    const int tid = threadIdx.x;
    const int w = tid >> 6, lane = tid & 63;
    const int wm = (w & 1) << 6, wn = (w >> 1) << 6;
    const int c = lane & 15, quad = lane >> 4;

    #pragma unroll
    for (int j = 0; j < 4; ++j) {
        const int n_g = n0 + wn + j * 16 + c;
        const float bj = bo[n_g];
        #pragma unroll
        for (int i = 0; i < 4; ++i) {
            const int mbase = m0 + wm + i * 16 + quad * 4;
            #pragma unroll
            for (int reg = 0; reg < 4; ++reg)
                out[(size_t)(mbase + reg) * HID + n_g] = acc[i][j][reg] + bj;
        }
    }
}

extern "C" void kernel_launch(void* const* d_in, const int* in_sizes, int n_in,
                              void* d_out, int out_size, void* d_ws, size_t ws_size,
                              hipStream_t stream)
{
    const float* x    = (const float*)d_in[0];
    const int*   mask = (const int*)d_in[1];
    const float* Wq   = (const float*)d_in[2];
    const float* bq   = (const float*)d_in[3];
    const float* Wk   = (const float*)d_in[4];
    const float* bk   = (const float*)d_in[5];
    const float* Wv   = (const float*)d_in[6];
    const float* bv   = (const float*)d_in[7];
    const float* Wo   = (const float*)d_in[8];
    const float* bo   = (const float*)d_in[9];
    float* out = (float*)d_out;

    ushort_t* p = (ushort_t*)d_ws;
    ushort_t* xb  = p; p += (size_t)MROWS * HID;
    ushort_t* wqb = p; p += (size_t)HID * HID;
    ushort_t* wkb = p; p += (size_t)HID * HID;
    ushort_t* wvb = p; p += (size_t)HID * HID;
    ushort_t* wob = p; p += (size_t)HID * HID;
    ushort_t* qb  = p; p += (size_t)MROWS * HID;
    ushort_t* kb  = p; p += (size_t)MROWS * HID;
    ushort_t* vtb = p; p += (size_t)MROWS * HID;
    ushort_t* aob = p; p += (size_t)MROWS * HID;

    cvt_bf16_kernel<<<dim3(512, 12), 256, 0, stream>>>(
        x, Wq, Wk, Wv, Wo, xb, wqb, wkb, wvb, wob);
    qkv_mfma_kernel<<<dim3(8, 64, 3), 256, 0, stream>>>(
        xb, wqb, wkb, wvb, bq, bk, bv, qb, kb, vtb);
    attn_mfma_kernel<<<dim3(16, 64), 256, 0, stream>>>(
        qb, kb, vtb, mask, aob);
    out_mfma_kernel<<<dim3(8, 64), 256, 0, stream>>>(
        aob, wob, bo, out);
}